// Round 3
// baseline (610.341 us; speedup 1.0000x reference)
//
#include <hip/hip_runtime.h>
#include <cstdint>
#include <cstddef>

// Problem constants (B=2, S=2048 -> T=4096 tokens)
#define TT 4096
#define DD 1024
#define MM 2048
#define EE 8
#define NPAIR 8192   // TT * top_k(2)

typedef unsigned short u16;
typedef __bf16 bf16x8 __attribute__((ext_vector_type(8)));
typedef float f32x4 __attribute__((ext_vector_type(4)));
typedef __attribute__((address_space(3))) void* lds_vp;
typedef __attribute__((address_space(1))) const void* gbl_cvp;

__device__ __forceinline__ void async16(u16* l, const u16* g) {
  __builtin_amdgcn_global_load_lds((gbl_cvp)(const void*)g, (lds_vp)(void*)l, 16, 0, 0);
}

__device__ __forceinline__ u16 f2bf(float f) {
  uint32_t u = __builtin_bit_cast(uint32_t, f);
  u += 0x7fffu + ((u >> 16) & 1u);   // RNE
  return (u16)(u >> 16);
}

// ---------------- router: logits -> softmax -> top2 -> renorm ----------------
__global__ void router_kernel(const float* __restrict__ X, const float* __restrict__ Wr,
                              int* __restrict__ tok_idx, float* __restrict__ wpair) {
  int wave = threadIdx.x >> 6;
  int lane = threadIdx.x & 63;
  int t = blockIdx.x * 4 + wave;
  const float4* x4 = (const float4*)(X + (size_t)t * DD);
  float acc[EE];
#pragma unroll
  for (int e = 0; e < EE; e++) acc[e] = 0.f;
#pragma unroll
  for (int i = 0; i < 4; i++) {
    float4 xv = x4[i * 64 + lane];
    const float4* wr4 = (const float4*)(Wr + (size_t)(i * 256 + lane * 4) * EE);
    float xs[4] = {xv.x, xv.y, xv.z, xv.w};
#pragma unroll
    for (int c = 0; c < 4; c++) {
      float4 wa = wr4[c * 2 + 0];
      float4 wb = wr4[c * 2 + 1];
      acc[0] += xs[c] * wa.x; acc[1] += xs[c] * wa.y;
      acc[2] += xs[c] * wa.z; acc[3] += xs[c] * wa.w;
      acc[4] += xs[c] * wb.x; acc[5] += xs[c] * wb.y;
      acc[6] += xs[c] * wb.z; acc[7] += xs[c] * wb.w;
    }
  }
#pragma unroll
  for (int off = 32; off > 0; off >>= 1)
#pragma unroll
    for (int e = 0; e < EE; e++) acc[e] += __shfl_xor(acc[e], off);
  if (lane == 0) {
    float mx = acc[0];
#pragma unroll
    for (int e = 1; e < EE; e++) mx = fmaxf(mx, acc[e]);
    float p[EE], s = 0.f;
#pragma unroll
    for (int e = 0; e < EE; e++) { p[e] = __expf(acc[e] - mx); s += p[e]; }
    float inv = 1.f / s;
#pragma unroll
    for (int e = 0; e < EE; e++) p[e] *= inv;
    int i0 = 0;
#pragma unroll
    for (int e = 1; e < EE; e++) if (p[e] > p[i0]) i0 = e;
    int i1 = (i0 == 0) ? 1 : 0;
#pragma unroll
    for (int e = 0; e < EE; e++) if (e != i0 && p[e] > p[i1]) i1 = e;
    float denom = p[i0] + p[i1] + 1e-8f;
    tok_idx[t * 2 + 0] = i0;
    tok_idx[t * 2 + 1] = i1;
    wpair[t * 2 + 0] = p[i0] / denom;
    wpair[t * 2 + 1] = p[i1] / denom;
  }
}

// ---------------- single-block bucketing via LDS atomics ----------------
__global__ void bucket_kernel(const int* __restrict__ tok_idx, int* __restrict__ offsets,
                              int* __restrict__ bucket) {
  __shared__ int lcnt[EE];
  __shared__ int lcur[EE];
  int tid = threadIdx.x;   // 1024 threads
  if (tid < EE) lcnt[tid] = 0;
  __syncthreads();
  for (int i = tid; i < NPAIR; i += 1024) atomicAdd(&lcnt[tok_idx[i]], 1);
  __syncthreads();
  if (tid == 0) {
    int s = 0;
    for (int e = 0; e < EE; e++) {
      offsets[e] = s;
      lcur[e] = s;
      s += lcnt[e];
    }
    offsets[EE] = s;
  }
  __syncthreads();
  for (int i = tid; i < NPAIR; i += 1024) {
    int e = tok_idx[i];
    int pos = atomicAdd(&lcur[e], 1);
    bucket[pos] = i;
  }
}

// ---------------- fp32 -> bf16 convert of residual ----------------
__global__ void cvtx_kernel(const float* __restrict__ X, u16* __restrict__ Xbf) {
  int i = blockIdx.x * 256 + threadIdx.x;
  float4 v = ((const float4*)X)[i];
  ushort4 o;
  o.x = f2bf(v.x); o.y = f2bf(v.y); o.z = f2bf(v.z); o.w = f2bf(v.w);
  ((ushort4*)Xbf)[i] = o;
}

// ---------------- transpose+convert: in [E][R][C] f32 -> out [E][C][R] bf16 ----------------
__global__ void transpose_cvt(const float* __restrict__ in, u16* __restrict__ out, int R, int C) {
  __shared__ float tile[32][33];
  int e = blockIdx.z;
  const float* I = in + (size_t)e * R * C;
  u16* O = out + (size_t)e * R * C;
  int c0 = blockIdx.x * 32, r0 = blockIdx.y * 32;
  for (int i = threadIdx.y; i < 32; i += 8)
    tile[i][threadIdx.x] = I[(size_t)(r0 + i) * C + c0 + threadIdx.x];
  __syncthreads();
  for (int i = threadIdx.y; i < 32; i += 8)
    O[(size_t)(c0 + i) * R + r0 + threadIdx.x] = f2bf(tile[threadIdx.x][i]);
}

// Map blockIdx.x -> (expert, row tile). Tiles never cross expert boundaries.
__device__ __forceinline__ bool tile_map(const int* __restrict__ offsets, int x,
                                         int& expert, int& row0, int& rows) {
  expert = -1;
#pragma unroll 1
  for (int e = 0; e < EE; e++) {
    int o0 = offsets[e], o1 = offsets[e + 1];
    int nt = (o1 - o0 + 127) >> 7;
    if (x < nt) { expert = e; row0 = o0 + (x << 7); rows = min(128, o1 - row0); return true; }
    x -= nt;
  }
  return false;
}

// LDS bank-conflict swizzle: chunk q of row r stored at position q ^ ((r>>1)&3).
// Staging lane (row = lane>>2, pos = lane&3) must LOAD global chunk pos ^ ((lane>>3)&3).
// (async16 dest is fixed wave-uniform-base + lane*16; we permute the SOURCE.)

// ---------------- fused gate+up GEMM ----------------
// H[grow][:] = silu(X*Wg + b_gate) * (X*Wu + b_up), rows in bucket order
__global__ __launch_bounds__(256)
void moe_gemm_gu(const u16* __restrict__ Xbf, const u16* __restrict__ Wg,
                 const float* __restrict__ bgate, const float* __restrict__ bup,
                 u16* __restrict__ Hws, const int* __restrict__ offsets,
                 const int* __restrict__ bucket) {
  constexpr int K = DD, N = MM;
  int expert, row0, rows;
  if (!tile_map(offsets, blockIdx.x, expert, row0, rows)) return;
  int n0 = blockIdx.y * 128;

  __shared__ u16 Alds[128 * 32];
  __shared__ u16 Glds[128 * 32];
  __shared__ u16 Ulds[128 * 32];

  int tid = threadIdx.x;
  int wave = tid >> 6, lane = tid & 63;
  int wm = wave >> 1, wn = wave & 1;
  int quad = lane >> 4, l15 = lane & 15;
  int swz = ((lane & 3) ^ ((lane >> 3) & 3)) * 8;   // source chunk (u16 elems)
  int rp  = (quad ^ ((l15 >> 1) & 3)) * 8;          // read chunk position (u16 elems)

  long arow0, arow1;
  {
    int r0l = wave * 32 + (lane >> 2);
    int rr0 = min(r0l, rows - 1);
    int rr1 = min(r0l + 16, rows - 1);
    arow0 = (long)(bucket[row0 + rr0] >> 1) * K;
    arow1 = (long)(bucket[row0 + rr1] >> 1) * K;
  }
  const u16* A0 = Xbf + arow0 + swz;
  const u16* A1 = Xbf + arow1 + swz;
  long woff = (size_t)expert * N * K + (size_t)n0 * K + (long)(wave * 32 + (lane >> 2)) * K + swz;
  const u16* G0 = Wg + woff;
  const u16* G1 = G0 + 16 * K;
  const u16* U0 = G0 + (size_t)EE * MM * DD;   // WtU is contiguous after WtG in ws
  const u16* U1 = U0 + 16 * K;

  u16* sA0 = &Alds[(wave * 32) * 32];      u16* sA1 = &Alds[(wave * 32 + 16) * 32];
  u16* sG0 = &Glds[(wave * 32) * 32];      u16* sG1 = &Glds[(wave * 32 + 16) * 32];
  u16* sU0 = &Ulds[(wave * 32) * 32];      u16* sU1 = &Ulds[(wave * 32 + 16) * 32];

  f32x4 ag[4][4], au[4][4];
#pragma unroll
  for (int i = 0; i < 4; i++)
#pragma unroll
    for (int j = 0; j < 4; j++) { ag[i][j] = (f32x4){0,0,0,0}; au[i][j] = (f32x4){0,0,0,0}; }

  for (int k0 = 0; k0 < K; k0 += 32) {
    async16(sA0, A0); async16(sA1, A1);
    async16(sG0, G0); async16(sG1, G1);
    async16(sU0, U0); async16(sU1, U1);
    A0 += 32; A1 += 32; G0 += 32; G1 += 32; U0 += 32; U1 += 32;
    __syncthreads();
    bf16x8 af[4], bg[4], bu[4];
#pragma unroll
    for (int i = 0; i < 4; i++) {
      af[i] = *(const bf16x8*)&Alds[(wm * 64 + i * 16 + l15) * 32 + rp];
      bg[i] = *(const bf16x8*)&Glds[(wn * 64 + i * 16 + l15) * 32 + rp];
      bu[i] = *(const bf16x8*)&Ulds[(wn * 64 + i * 16 + l15) * 32 + rp];
    }
#pragma unroll
    for (int i = 0; i < 4; i++)
#pragma unroll
      for (int j = 0; j < 4; j++) {
        ag[i][j] = __builtin_amdgcn_mfma_f32_16x16x32_bf16(af[i], bg[j], ag[i][j], 0, 0, 0);
        au[i][j] = __builtin_amdgcn_mfma_f32_16x16x32_bf16(af[i], bu[j], au[i][j], 0, 0, 0);
      }
    __syncthreads();
  }

  // epilogue: C/D layout col = lane&15, row = quad*4 + r
#pragma unroll
  for (int i = 0; i < 4; i++) {
    int lrb = wm * 64 + i * 16 + quad * 4;
#pragma unroll
    for (int j = 0; j < 4; j++) {
      int gc = n0 + wn * 64 + j * 16 + l15;
      float bgv = bgate[expert * N + gc];
      float buv = bup[expert * N + gc];
#pragma unroll
      for (int r = 0; r < 4; r++) {
        int lr = lrb + r;
        if (lr < rows) {
          int grow = row0 + lr;
          float g = ag[i][j][r] + bgv;
          float u = au[i][j][r] + buv;
          float h = (g / (1.f + __expf(-g))) * u;
          Hws[(size_t)grow * MM + gc] = f2bf(h);
        }
      }
    }
  }
}

// ---------------- output GEMM: out[t] += w * (H*Wo + b_out) ----------------
__global__ __launch_bounds__(256)
void moe_gemm_out(const u16* __restrict__ Hws, const u16* __restrict__ Wo,
                  const float* __restrict__ bout, float* __restrict__ out,
                  const int* __restrict__ offsets, const int* __restrict__ bucket,
                  const float* __restrict__ wpair) {
  constexpr int K = MM, N = DD;
  int expert, row0, rows;
  if (!tile_map(offsets, blockIdx.x, expert, row0, rows)) return;
  int n0 = blockIdx.y * 128;

  __shared__ u16 Alds[128 * 32];
  __shared__ u16 Blds[128 * 32];

  int tid = threadIdx.x;
  int wave = tid >> 6, lane = tid & 63;
  int wm = wave >> 1, wn = wave & 1;
  int quad = lane >> 4, l15 = lane & 15;
  int swz = ((lane & 3) ^ ((lane >> 3) & 3)) * 8;
  int rp  = (quad ^ ((l15 >> 1) & 3)) * 8;

  long arow0, arow1;
  {
    int r0l = wave * 32 + (lane >> 2);
    int rr0 = min(r0l, rows - 1);
    int rr1 = min(r0l + 16, rows - 1);
    arow0 = (long)(row0 + rr0) * K;   // Hws already in bucket-row order
    arow1 = (long)(row0 + rr1) * K;
  }
  const u16* A0 = Hws + arow0 + swz;
  const u16* A1 = Hws + arow1 + swz;
  const u16* B0 = Wo + (size_t)expert * N * K + (size_t)n0 * K + (long)(wave * 32 + (lane >> 2)) * K + swz;
  const u16* B1 = B0 + 16 * K;

  u16* sA0 = &Alds[(wave * 32) * 32]; u16* sA1 = &Alds[(wave * 32 + 16) * 32];
  u16* sB0 = &Blds[(wave * 32) * 32]; u16* sB1 = &Blds[(wave * 32 + 16) * 32];

  f32x4 acc[4][4];
#pragma unroll
  for (int i = 0; i < 4; i++)
#pragma unroll
    for (int j = 0; j < 4; j++) acc[i][j] = (f32x4){0, 0, 0, 0};

  for (int k0 = 0; k0 < K; k0 += 32) {
    async16(sA0, A0); async16(sA1, A1);
    async16(sB0, B0); async16(sB1, B1);
    A0 += 32; A1 += 32; B0 += 32; B1 += 32;
    __syncthreads();
    bf16x8 af[4], bf[4];
#pragma unroll
    for (int i = 0; i < 4; i++) {
      af[i] = *(const bf16x8*)&Alds[(wm * 64 + i * 16 + l15) * 32 + rp];
      bf[i] = *(const bf16x8*)&Blds[(wn * 64 + i * 16 + l15) * 32 + rp];
    }
#pragma unroll
    for (int i = 0; i < 4; i++)
#pragma unroll
      for (int j = 0; j < 4; j++)
        acc[i][j] = __builtin_amdgcn_mfma_f32_16x16x32_bf16(af[i], bf[j], acc[i][j], 0, 0, 0);
    __syncthreads();
  }

#pragma unroll
  for (int i = 0; i < 4; i++) {
    int lrb = wm * 64 + i * 16 + quad * 4;
#pragma unroll
    for (int j = 0; j < 4; j++) {
      int gc = n0 + wn * 64 + j * 16 + l15;
      float bv = bout[expert * N + gc];
#pragma unroll
      for (int r = 0; r < 4; r++) {
        int lr = lrb + r;
        if (lr < rows) {
          int grow = row0 + lr;
          int p = bucket[grow];
          float w = wpair[p];
          atomicAdd(&out[(size_t)(p >> 1) * DD + gc], w * (acc[i][j][r] + bv));
        }
      }
    }
  }
}

extern "C" void kernel_launch(void* const* d_in, const int* in_sizes, int n_in,
                              void* d_out, int out_size, void* d_ws, size_t ws_size,
                              hipStream_t stream) {
  const float* residual = (const float*)d_in[0];
  const float* W_router = (const float*)d_in[1];
  const float* W_gate   = (const float*)d_in[2];
  const float* b_gate   = (const float*)d_in[3];
  const float* W_up     = (const float*)d_in[4];
  const float* b_up     = (const float*)d_in[5];
  const float* W_out    = (const float*)d_in[6];
  const float* b_out    = (const float*)d_in[7];
  float* out = (float*)d_out;

  char* ws = (char*)d_ws;
  int*   tok_idx = (int*)(ws + 0);                       // 8192 ints
  float* wpair   = (float*)(ws + 32768);                 // 8192 floats
  int*   offsets = (int*)(ws + 65536);                   // 9 ints
  int*   bucket  = (int*)(ws + 65536 + 512);             // 8192 ints
  u16*   Xbf  = (u16*)(ws + 131072);                                     // 8 MB
  u16*   WtG  = Xbf + (size_t)TT * DD;                                   // 32 MB  [E][M][D]
  u16*   WtU  = WtG + (size_t)EE * MM * DD;                              // 32 MB  [E][M][D]  (must follow WtG!)
  u16*   WtO  = WtU + (size_t)EE * MM * DD;                              // 32 MB  [E][D][M]
  u16*   Hws  = WtO + (size_t)EE * DD * MM;                              // 32 MB  [8192][M]

  // out accumulated via atomics -> zero it
  hipMemsetAsync(out, 0, (size_t)out_size * sizeof(float), stream);

  cvtx_kernel<<<dim3(TT * DD / 4 / 256), dim3(256), 0, stream>>>(residual, Xbf);
  transpose_cvt<<<dim3(MM / 32, DD / 32, EE), dim3(32, 8), 0, stream>>>(W_gate, WtG, DD, MM);
  transpose_cvt<<<dim3(MM / 32, DD / 32, EE), dim3(32, 8), 0, stream>>>(W_up,   WtU, DD, MM);
  transpose_cvt<<<dim3(DD / 32, MM / 32, EE), dim3(32, 8), 0, stream>>>(W_out,  WtO, MM, DD);
  router_kernel<<<dim3(TT / 4), dim3(256), 0, stream>>>(residual, W_router, tok_idx, wpair);
  bucket_kernel<<<dim3(1), dim3(1024), 0, stream>>>(tok_idx, offsets, bucket);
  // grouped GEMMs: max row tiles = 64 + 8 = 72
  moe_gemm_gu<<<dim3(72, MM / 128), dim3(256), 0, stream>>>(Xbf, WtG, b_gate, b_up, Hws, offsets, bucket);
  moe_gemm_out<<<dim3(72, DD / 128), dim3(256), 0, stream>>>(Hws, WtO, b_out, out, offsets, bucket, wpair);
}

// Round 4
// 479.203 us; speedup vs baseline: 1.2737x; 1.2737x over previous
//
#include <hip/hip_runtime.h>
#include <cstdint>
#include <cstddef>

// Problem constants (B=2, S=2048 -> T=4096 tokens)
#define TT 4096
#define DD 1024
#define MM 2048
#define EE 8
#define NPAIR 8192   // TT * top_k(2)

typedef unsigned short u16;
typedef __bf16 bf16x8 __attribute__((ext_vector_type(8)));
typedef float f32x4 __attribute__((ext_vector_type(4)));
typedef u16 u16x8 __attribute__((ext_vector_type(8)));
typedef __attribute__((address_space(3))) void* lds_vp;
typedef __attribute__((address_space(1))) const void* gbl_cvp;

__device__ __forceinline__ void async16(u16* l, const u16* g) {
  __builtin_amdgcn_global_load_lds((gbl_cvp)(const void*)g, (lds_vp)(void*)l, 16, 0, 0);
}

__device__ __forceinline__ u16 f2bf(float f) {
  uint32_t u = __builtin_bit_cast(uint32_t, f);
  u += 0x7fffu + ((u >> 16) & 1u);   // RNE
  return (u16)(u >> 16);
}
__device__ __forceinline__ float bf2f(u16 h) {
  uint32_t u = ((uint32_t)h) << 16;
  return __builtin_bit_cast(float, u);
}

// ---------------- router + X->bf16 convert fused ----------------
// one wave per token; wave already holds the whole row, so emit Xbf for free.
__global__ void router_kernel(const float* __restrict__ X, const float* __restrict__ Wr,
                              int* __restrict__ tok_idx, float* __restrict__ wpair,
                              u16* __restrict__ Xbf) {
  int wave = threadIdx.x >> 6;
  int lane = threadIdx.x & 63;
  int t = blockIdx.x * 4 + wave;
  const float4* x4 = (const float4*)(X + (size_t)t * DD);
  float acc[EE];
#pragma unroll
  for (int e = 0; e < EE; e++) acc[e] = 0.f;
#pragma unroll
  for (int i = 0; i < 4; i++) {
    float4 xv = x4[i * 64 + lane];
    // bf16 conversion side-channel (coalesced 8B stores)
    ushort4 o;
    o.x = f2bf(xv.x); o.y = f2bf(xv.y); o.z = f2bf(xv.z); o.w = f2bf(xv.w);
    *(ushort4*)&Xbf[(size_t)t * DD + (size_t)(i * 64 + lane) * 4] = o;
    const float4* wr4 = (const float4*)(Wr + (size_t)(i * 256 + lane * 4) * EE);
    float xs[4] = {xv.x, xv.y, xv.z, xv.w};
#pragma unroll
    for (int c = 0; c < 4; c++) {
      float4 wa = wr4[c * 2 + 0];
      float4 wb = wr4[c * 2 + 1];
      acc[0] += xs[c] * wa.x; acc[1] += xs[c] * wa.y;
      acc[2] += xs[c] * wa.z; acc[3] += xs[c] * wa.w;
      acc[4] += xs[c] * wb.x; acc[5] += xs[c] * wb.y;
      acc[6] += xs[c] * wb.z; acc[7] += xs[c] * wb.w;
    }
  }
#pragma unroll
  for (int off = 32; off > 0; off >>= 1)
#pragma unroll
    for (int e = 0; e < EE; e++) acc[e] += __shfl_xor(acc[e], off);
  if (lane == 0) {
    float mx = acc[0];
#pragma unroll
    for (int e = 1; e < EE; e++) mx = fmaxf(mx, acc[e]);
    float p[EE], s = 0.f;
#pragma unroll
    for (int e = 0; e < EE; e++) { p[e] = __expf(acc[e] - mx); s += p[e]; }
    float inv = 1.f / s;
#pragma unroll
    for (int e = 0; e < EE; e++) p[e] *= inv;
    int i0 = 0;
#pragma unroll
    for (int e = 1; e < EE; e++) if (p[e] > p[i0]) i0 = e;
    int i1 = (i0 == 0) ? 1 : 0;
#pragma unroll
    for (int e = 0; e < EE; e++) if (e != i0 && p[e] > p[i1]) i1 = e;
    float denom = p[i0] + p[i1] + 1e-8f;
    tok_idx[t * 2 + 0] = i0;
    tok_idx[t * 2 + 1] = i1;
    wpair[t * 2 + 0] = p[i0] / denom;
    wpair[t * 2 + 1] = p[i1] / denom;
  }
}

// ---------------- single-block bucketing via LDS atomics ----------------
__global__ void bucket_kernel(const int* __restrict__ tok_idx, int* __restrict__ offsets,
                              int* __restrict__ bucket) {
  __shared__ int lcnt[EE];
  __shared__ int lcur[EE];
  int tid = threadIdx.x;   // 1024 threads
  if (tid < EE) lcnt[tid] = 0;
  __syncthreads();
  for (int i = tid; i < NPAIR; i += 1024) atomicAdd(&lcnt[tok_idx[i]], 1);
  __syncthreads();
  if (tid == 0) {
    int s = 0;
    for (int e = 0; e < EE; e++) {
      offsets[e] = s;
      lcur[e] = s;
      s += lcnt[e];
    }
    offsets[EE] = s;
  }
  __syncthreads();
  for (int i = tid; i < NPAIR; i += 1024) {
    int e = tok_idx[i];
    int pos = atomicAdd(&lcur[e], 1);
    bucket[pos] = i;
  }
}

// ---------------- transpose+convert: in [E][R][C] f32 -> out [E][C][R] bf16 ----------------
// 64x64 tiles, float4 loads, 16B ushort8 stores (old 32x32 version was 2B-store bound)
__global__ __launch_bounds__(256)
void transpose_cvt(const float* __restrict__ in, u16* __restrict__ out, int R, int C) {
  __shared__ float tile[64][65];   // [c][r], +1 pad
  int e = blockIdx.z;
  const float* I = in + (size_t)e * R * C;
  u16* O = out + (size_t)e * R * C;
  int c0 = blockIdx.x * 64, r0 = blockIdx.y * 64;
  int t = threadIdx.x;
  {
    int cq = t & 15;          // col quad
    int rb = t >> 4;          // row base
#pragma unroll
    for (int i = 0; i < 4; i++) {
      int r = rb + i * 16;
      float4 v = *(const float4*)&I[(size_t)(r0 + r) * C + c0 + cq * 4];
      tile[cq * 4 + 0][r] = v.x;
      tile[cq * 4 + 1][r] = v.y;
      tile[cq * 4 + 2][r] = v.z;
      tile[cq * 4 + 3][r] = v.w;
    }
  }
  __syncthreads();
  {
    int rseg = (t & 7) * 8;
    int cc = t >> 3;          // 0..31
#pragma unroll
    for (int i = 0; i < 2; i++) {
      int c = cc + i * 32;
      u16x8 o;
#pragma unroll
      for (int k = 0; k < 8; k++) o[k] = f2bf(tile[c][rseg + k]);
      *(u16x8*)&O[(size_t)(c0 + c) * R + r0 + rseg] = o;
    }
  }
}

// Map row-tile index rt -> (expert, row0, rows). Tiles never cross expert boundaries.
__device__ __forceinline__ bool tile_map(const int* __restrict__ offsets, int x,
                                         int& expert, int& row0, int& rows) {
  expert = -1;
#pragma unroll 1
  for (int e = 0; e < EE; e++) {
    int o0 = offsets[e], o1 = offsets[e + 1];
    int nt = (o1 - o0 + 127) >> 7;
    if (x < nt) { expert = e; row0 = o0 + (x << 7); rows = min(128, o1 - row0); return true; }
    x -= nt;
  }
  return false;
}

// XCD-aware 1D grid decode: each XCD (bid&7) owns 9 consecutive row tiles and
// sweeps n-tiles innermost -> A strip stays L2-resident, B tiles re-swept hot.
// NTLOG2: log2(number of n tiles).
template <int NTLOG2>
__device__ __forceinline__ void grid_decode(int bid, int& rt, int& n0) {
  int xcd = bid & 7, slot = bid >> 3;
  rt = xcd * 9 + (slot >> NTLOG2);
  n0 = (slot & ((1 << NTLOG2) - 1)) * 128;
}

// LDS bank-conflict swizzle (verified R3: conflicts 4.4M -> 0):
// chunk q of row r stored at position q ^ ((r>>1)&3); staging lane permutes SOURCE chunk.

// ---------------- grouped MFMA GEMM ----------------
// MODE 0: U = X*Wu + b_up            -> Hws (bf16)
// MODE 1: H = silu(X*Wg + b_gate)*U  -> Hws (bf16, in place over U)
// MODE 2: Ypart[pair] = w*(H*Wo + b_out)  (f32)
template <int MODE>
__global__ __launch_bounds__(256)
void moe_gemm(const u16* __restrict__ Aglob, const u16* __restrict__ Wt,
              const float* __restrict__ bias, u16* __restrict__ Hws,
              float* __restrict__ Ypart, const int* __restrict__ offsets,
              const int* __restrict__ bucket, const float* __restrict__ wpair) {
  constexpr int K = (MODE == 2) ? MM : DD;
  constexpr int N = (MODE == 2) ? DD : MM;

  int rt, n0;
  grid_decode<(MODE == 2) ? 3 : 4>(blockIdx.x, rt, n0);
  int expert, row0, rows;
  if (!tile_map(offsets, rt, expert, row0, rows)) return;

  __shared__ u16 Alds[128 * 32];
  __shared__ u16 Blds[128 * 32];

  int tid = threadIdx.x;
  int wave = tid >> 6, lane = tid & 63;
  int wm = wave >> 1, wn = wave & 1;
  int quad = lane >> 4, l15 = lane & 15;
  int swz = ((lane & 3) ^ ((lane >> 3) & 3)) * 8;   // global source chunk
  int rp  = (quad ^ ((l15 >> 1) & 3)) * 8;          // LDS read chunk position

  long arow0, arow1;
  {
    int r0l = wave * 32 + (lane >> 2);
    int rr0 = min(r0l, rows - 1);
    int rr1 = min(r0l + 16, rows - 1);
    if (MODE == 2) {
      arow0 = (long)(row0 + rr0) * K;   // Hws already in bucket-row order
      arow1 = (long)(row0 + rr1) * K;
    } else {
      arow0 = (long)(bucket[row0 + rr0] >> 1) * K;
      arow1 = (long)(bucket[row0 + rr1] >> 1) * K;
    }
  }
  const u16* A0 = Aglob + arow0 + swz;
  const u16* A1 = Aglob + arow1 + swz;
  const u16* B0 = Wt + (size_t)expert * N * K + (size_t)n0 * K
                  + (long)(wave * 32 + (lane >> 2)) * K + swz;
  const u16* B1 = B0 + 16 * K;

  u16* sA0 = &Alds[(wave * 32) * 32]; u16* sA1 = &Alds[(wave * 32 + 16) * 32];
  u16* sB0 = &Blds[(wave * 32) * 32]; u16* sB1 = &Blds[(wave * 32 + 16) * 32];

  f32x4 acc[4][4];
#pragma unroll
  for (int i = 0; i < 4; i++)
#pragma unroll
    for (int j = 0; j < 4; j++) acc[i][j] = (f32x4){0, 0, 0, 0};

  for (int k0 = 0; k0 < K; k0 += 32) {
    async16(sA0, A0); async16(sA1, A1);
    async16(sB0, B0); async16(sB1, B1);
    A0 += 32; A1 += 32; B0 += 32; B1 += 32;
    __syncthreads();
    bf16x8 af[4], bf[4];
#pragma unroll
    for (int i = 0; i < 4; i++) {
      af[i] = *(const bf16x8*)&Alds[(wm * 64 + i * 16 + l15) * 32 + rp];
      bf[i] = *(const bf16x8*)&Blds[(wn * 64 + i * 16 + l15) * 32 + rp];
    }
#pragma unroll
    for (int i = 0; i < 4; i++)
#pragma unroll
      for (int j = 0; j < 4; j++)
        acc[i][j] = __builtin_amdgcn_mfma_f32_16x16x32_bf16(af[i], bf[j], acc[i][j], 0, 0, 0);
    __syncthreads();
  }

  // epilogue: C/D layout col = lane&15, row = quad*4 + r
#pragma unroll
  for (int i = 0; i < 4; i++) {
    int lrb = wm * 64 + i * 16 + quad * 4;
#pragma unroll
    for (int j = 0; j < 4; j++) {
      int gc = n0 + wn * 64 + j * 16 + l15;
      float bv = bias[expert * N + gc];
#pragma unroll
      for (int r = 0; r < 4; r++) {
        int lr = lrb + r;
        if (lr < rows) {
          int grow = row0 + lr;
          float v = acc[i][j][r] + bv;
          if (MODE == 0) {
            Hws[(size_t)grow * MM + gc] = f2bf(v);
          } else if (MODE == 1) {
            float u = bf2f(Hws[(size_t)grow * MM + gc]);
            float sg = v / (1.f + __expf(-v));
            Hws[(size_t)grow * MM + gc] = f2bf(sg * u);
          } else {
            int p = bucket[grow];
            float w = wpair[p];
            Ypart[(size_t)p * DD + gc] = w * v;
          }
        }
      }
    }
  }
}

// ---------------- combine the two expert contributions per token ----------------
__global__ void combine_kernel(const float* __restrict__ Ypart, float* __restrict__ out) {
  int i = blockIdx.x * 256 + threadIdx.x;   // over TT*DD/4
  int t = i >> 8;          // DD/4 = 256 float4 per token
  int c4 = i & 255;
  const float4* y0 = (const float4*)(Ypart + (size_t)(2 * t) * DD) + c4;
  const float4* y1 = (const float4*)(Ypart + (size_t)(2 * t + 1) * DD) + c4;
  float4 a = *y0, b = *y1;
  float4 o;
  o.x = a.x + b.x; o.y = a.y + b.y; o.z = a.z + b.z; o.w = a.w + b.w;
  ((float4*)out)[i] = o;
}

extern "C" void kernel_launch(void* const* d_in, const int* in_sizes, int n_in,
                              void* d_out, int out_size, void* d_ws, size_t ws_size,
                              hipStream_t stream) {
  const float* residual = (const float*)d_in[0];
  const float* W_router = (const float*)d_in[1];
  const float* W_gate   = (const float*)d_in[2];
  const float* b_gate   = (const float*)d_in[3];
  const float* W_up     = (const float*)d_in[4];
  const float* b_up     = (const float*)d_in[5];
  const float* W_out    = (const float*)d_in[6];
  const float* b_out    = (const float*)d_in[7];
  float* out = (float*)d_out;

  char* ws = (char*)d_ws;
  int*   tok_idx = (int*)(ws + 0);                       // 8192 ints
  float* wpair   = (float*)(ws + 32768);                 // 8192 floats
  int*   offsets = (int*)(ws + 65536);                   // 9 ints
  int*   bucket  = (int*)(ws + 65536 + 512);             // 8192 ints
  u16*   Xbf  = (u16*)(ws + 131072);                                     // 8 MB
  u16*   WtG  = Xbf + (size_t)TT * DD;                                   // 32 MB  [E][M][D]
  u16*   WtU  = WtG + (size_t)EE * MM * DD;                              // 32 MB  [E][M][D]
  u16*   WtO  = WtU + (size_t)EE * MM * DD;                              // 32 MB  [E][D][M]
  u16*   Hws  = WtO + (size_t)EE * DD * MM;                              // 32 MB  [8192][M]
  float* Ypart = (float*)(Hws + (size_t)NPAIR * MM);                     // 32 MB  [8192][D]

  // routing (+ X->bf16 fused)
  router_kernel<<<dim3(TT / 4), dim3(256), 0, stream>>>(residual, W_router, tok_idx, wpair, Xbf);
  bucket_kernel<<<dim3(1), dim3(1024), 0, stream>>>(tok_idx, offsets, bucket);
  // weight transposes (K-contiguous bf16)
  transpose_cvt<<<dim3(MM / 64, DD / 64, EE), dim3(256), 0, stream>>>(W_gate, WtG, DD, MM);
  transpose_cvt<<<dim3(MM / 64, DD / 64, EE), dim3(256), 0, stream>>>(W_up,   WtU, DD, MM);
  transpose_cvt<<<dim3(DD / 64, MM / 64, EE), dim3(256), 0, stream>>>(W_out,  WtO, MM, DD);
  // grouped GEMMs: 8 XCD-sets x 9 row tiles x n-tiles
  moe_gemm<0><<<dim3(8 * 9 * 16), dim3(256), 0, stream>>>(Xbf, WtU, b_up,   Hws, Ypart, offsets, bucket, wpair);
  moe_gemm<1><<<dim3(8 * 9 * 16), dim3(256), 0, stream>>>(Xbf, WtG, b_gate, Hws, Ypart, offsets, bucket, wpair);
  moe_gemm<2><<<dim3(8 * 9 * 8),  dim3(256), 0, stream>>>(Hws, WtO, b_out,  Hws, Ypart, offsets, bucket, wpair);
  // combine
  combine_kernel<<<dim3(TT * DD / 4 / 256), dim3(256), 0, stream>>>(Ypart, out);
}